// Round 6
// baseline (214.363 us; speedup 1.0000x reference)
//
#include <hip/hip_runtime.h>
#include <math.h>

#define Bb 8
#define Hh 8
#define LQ 2048
#define LK 2048
#define Dd 64
#define Uu 40
#define NCH 32
#define CHUNK (LK / NCH)   // 64
#define NSPL 8
#define CK (LK / NSPL)     // 256 keys per split-K chunk
#define UW 10              // queries per wave in k_attn_part

__device__ __forceinline__ float dot4(float4 a, float4 b) {
    return a.x * b.x + a.y * b.y + a.z * b.z + a.w * b.w;
}

// ---------------- Stage 1: M[b,h,q] = max_s(QK_s) - mean_s(QK_s) ----------------
// block = (b, 16 queries). Dense-coalesced gather: lane owns ONE float4 at lane*16B,
// so each dwordx4 is a contiguous 1KB burst. Load A = heads 0-3, load B = heads 4-7.
// lane's fragment: head lane>>4, d-slice (lane&15)*4; reduce over 16-lane groups.
__global__ __launch_bounds__(256) void k_sampleM(
    const float* __restrict__ Qp, const float* __restrict__ Kp,
    const int* __restrict__ idxs, float* __restrict__ M)
{
    int b  = blockIdx.x & 7;      // b-major: round-robin XCD dispatch pins K[b] (4MB) per XCD L2
    int qt = blockIdx.x >> 3;     // 0..127 (16 queries per block)
    int t = threadIdx.x;
    int lane = t & 63, wave = t >> 6;

    __shared__ int sIdx[16 * Uu];
    for (int i = t; i < 16 * Uu; i += 256)
        sIdx[i] = idxs[(qt * 16) * Uu + i];
    __syncthreads();

    const size_t HD = (size_t)Hh * Dd;   // 512
#pragma unroll
    for (int i = 0; i < 4; ++i) {
        int lq = wave * 4 + i;
        int q  = qt * 16 + lq;
        const float4* Qv = reinterpret_cast<const float4*>(
            Qp + ((size_t)b * LQ + q) * HD) + lane;
        float4 qa = Qv[0];        // heads 0-3: float offset lane*4
        float4 qb = Qv[64];       // heads 4-7: +256 floats

        float mxA = -INFINITY, smA = 0.f, mxB = -INFINITY, smB = 0.f;
#pragma unroll 8
        for (int s = 0; s < Uu; ++s) {
            int kidx = sIdx[lq * Uu + s];
            const float4* Kv = reinterpret_cast<const float4*>(
                Kp + ((size_t)b * LK + kidx) * HD) + lane;
            float4 ka = Kv[0];
            float4 kb = Kv[64];
            float pA = dot4(qa, ka);
            float pB = dot4(qb, kb);
            pA += __shfl_xor(pA, 1, 64);  pB += __shfl_xor(pB, 1, 64);
            pA += __shfl_xor(pA, 2, 64);  pB += __shfl_xor(pB, 2, 64);
            pA += __shfl_xor(pA, 4, 64);  pB += __shfl_xor(pB, 4, 64);
            pA += __shfl_xor(pA, 8, 64);  pB += __shfl_xor(pB, 8, 64);
            mxA = fmaxf(mxA, pA); smA += pA;
            mxB = fmaxf(mxB, pB); smB += pB;
        }
        if ((lane & 15) == 0) {
            int hA = lane >> 4;          // 0..3
            M[((b * 8 + hA) << 11) + q]     = mxA - smA * (1.0f / Uu);
            M[((b * 8 + hA + 4) << 11) + q] = mxB - smB * (1.0f / Uu);
        }
    }
}

// ---------------- Stage 2: top-40 per (b,h) — single wave, shuffle argmax ----------------
__global__ __launch_bounds__(64) void k_topk(
    const float* __restrict__ M, int* __restrict__ Mtop, int* __restrict__ sel)
{
    int bh = blockIdx.x;
    int lane = threadIdx.x;
    __shared__ float Ml[LQ];

    for (int j = lane; j < LQ; j += 64) {
        Ml[j] = M[bh * LQ + j];
        sel[bh * LQ + j] = -1;
    }
    __syncthreads();

    float lv = -INFINITY; int li = LQ;
    for (int j = 0; j < 32; ++j) {
        int idx = lane + 64 * j;
        float x = Ml[idx];
        if (x > lv) { lv = x; li = idx; }
    }

    for (int u = 0; u < Uu; ++u) {
        float v = lv; int id = li;
#pragma unroll
        for (int off = 32; off > 0; off >>= 1) {
            float ov = __shfl_xor(v, off, 64);
            int   oi = __shfl_xor(id, off, 64);
            if (ov > v || (ov == v && oi < id)) { v = ov; id = oi; }
        }
        if (lane == 0) {
            Mtop[bh * Uu + u] = id;
            sel[bh * LQ + id] = u;
        }
        if ((id & 63) == lane) {        // owner invalidates + rescans its column
            Ml[id] = -INFINITY;
            lv = -INFINITY; li = LQ;
            for (int j = 0; j < 32; ++j) {
                int idx = lane + 64 * j;
                float x = Ml[idx];
                if (x > lv) { lv = x; li = idx; }
            }
        }
    }
}

// ---------------- Stage 3: split-K partial attention (no max-sub softmax) ----------------
__global__ __launch_bounds__(256) void k_attn_part(
    const float* __restrict__ Qp, const float* __restrict__ Kp,
    const float* __restrict__ Vp, const int* __restrict__ Mtop,
    float* __restrict__ pacc, float* __restrict__ pl)
{
    int bh = blockIdx.x >> 3;
    int c  = blockIdx.x & (NSPL - 1);
    int b = bh >> 3, h = bh & 7;
    int lane = threadIdx.x & 63, wave = threadIdx.x >> 6;

    __shared__ float sQ[Uu][Dd];
    __shared__ int   sP[Uu];
    __shared__ float sE[4][UW][Dd];

    if (threadIdx.x < Uu) sP[threadIdx.x] = Mtop[bh * Uu + threadIdx.x];
    __syncthreads();
    for (int i = threadIdx.x; i < Uu * Dd; i += 256) {
        int u = i >> 6, d = i & 63;
        sQ[u][d] = Qp[(((size_t)b * LQ + sP[u]) * Hh + h) * Dd + d];
    }
    __syncthreads();

    float acc[UW], lsum[UW];
#pragma unroll
    for (int i = 0; i < UW; ++i) { acc[i] = 0.f; lsum[i] = 0.f; }

    const int u0 = wave * UW;
    for (int t = 0; t < CK / 64; ++t) {
        int k0 = c * CK + t * 64;
        int k  = k0 + lane;

        int need = 0;
#pragma unroll
        for (int uu = 0; uu < UW; ++uu) need |= (sP[u0 + uu] >= k0) ? 1 : 0;
        if (!need) continue;   // wave-uniform skip

        const float4* Kv = reinterpret_cast<const float4*>(
            Kp + (((size_t)b * LK + k) * Hh + h) * Dd);
        float4 kr[16];
#pragma unroll
        for (int j = 0; j < 16; ++j) kr[j] = Kv[j];

#pragma unroll
        for (int uu = 0; uu < UW; ++uu) {
            int p = sP[u0 + uu];
            if (p < k0) continue;
            const float4* Q4 = reinterpret_cast<const float4*>(sQ[u0 + uu]);
            float s = 0.f;
#pragma unroll
            for (int j = 0; j < 16; ++j) s += dot4(kr[j], Q4[j]);
            float e = (k <= p) ? __expf(s * 0.125f) : 0.f;
            sE[wave][uu][lane] = e;
        }

        const float* Vb = Vp + (((size_t)b * LK + k0) * Hh + h) * Dd + lane;
        float vc[64];
#pragma unroll
        for (int kk = 0; kk < 64; ++kk) vc[kk] = Vb[(size_t)kk * (Hh * Dd)];

#pragma unroll
        for (int uu = 0; uu < UW; ++uu) {
            int p = sP[u0 + uu];
            if (p < k0) continue;
            const float4* E4 = reinterpret_cast<const float4*>(sE[wave][uu]);
            float a = acc[uu], L = lsum[uu];
#pragma unroll
            for (int j = 0; j < 16; ++j) {
                float4 e4 = E4[j];
                a += e4.x * vc[4 * j + 0] + e4.y * vc[4 * j + 1]
                   + e4.z * vc[4 * j + 2] + e4.w * vc[4 * j + 3];
                L += (e4.x + e4.y) + (e4.z + e4.w);
            }
            acc[uu] = a; lsum[uu] = L;
        }
    }

#pragma unroll
    for (int uu = 0; uu < UW; ++uu) {
        int u = u0 + uu;
        pacc[(((size_t)bh * NSPL + c) * Uu + u) * Dd + lane] = acc[uu];
        if (lane == 0) pl[((size_t)bh * NSPL + c) * Uu + u] = lsum[uu];
    }
}

// ---------------- Stage 4a: per-chunk partial sums of V (float4, 16dq x 4r) -------------
__global__ __launch_bounds__(64) void k_part(
    const float* __restrict__ Vp, float* __restrict__ part)
{
    int c  = blockIdx.x & (NCH - 1);
    int bh = blockIdx.x >> 5;
    int b = bh >> 3, h = bh & 7;
    int dq = threadIdx.x & 15, r = threadIdx.x >> 4;

    const float* vb = Vp + (((size_t)b * LK + c * CHUNK) * Hh + h) * Dd + dq * 4;
    float sx = 0.f, sy = 0.f, sz = 0.f, sw = 0.f;
    for (int l = r; l < CHUNK; l += 4) {
        float4 v = *reinterpret_cast<const float4*>(vb + (size_t)l * (Hh * Dd));
        sx += v.x; sy += v.y; sz += v.z; sw += v.w;
    }
    sx += __shfl_xor(sx, 16, 64); sy += __shfl_xor(sy, 16, 64);
    sz += __shfl_xor(sz, 16, 64); sw += __shfl_xor(sw, 16, 64);
    sx += __shfl_xor(sx, 32, 64); sy += __shfl_xor(sy, 32, 64);
    sz += __shfl_xor(sz, 32, 64); sw += __shfl_xor(sw, 32, 64);
    if (r == 0) {
        float4 s4 = make_float4(sx, sy, sz, sw);
        *reinterpret_cast<float4*>(&part[(size_t)(bh * NCH + c) * Dd + dq * 4]) = s4;
    }
}

// ---------------- Stage 4b: cumsum + inline prefix + inline split-K combine -------------
__global__ __launch_bounds__(64) void k_scan(
    const float* __restrict__ Vp, const float* __restrict__ part,
    const int* __restrict__ sel, const float* __restrict__ pacc,
    const float* __restrict__ pl, float* __restrict__ out)
{
    int c  = blockIdx.x & (NCH - 1);
    int bh = blockIdx.x >> 5;
    int b = bh >> 3, h = bh & 7;
    int d = threadIdx.x;

    float run = 0.f;
    for (int cc = 0; cc < c; ++cc)
        run += part[(size_t)(bh * NCH + cc) * Dd + d];

    int l0 = c * CHUNK;
    const float* vb = Vp + (((size_t)b * LK + l0) * Hh + h) * Dd + d;
    float* ob = out + (((size_t)b * LQ + l0) * Hh + h) * Dd + d;
    const int* sb = sel + bh * LQ + l0;

    for (int l = 0; l < CHUNK; ++l) {
        float v = vb[(size_t)l * (Hh * Dd)];
        run += v;
        int s = sb[l];                  // uniform across the 64 d-threads
        float o = run;
        if (s >= 0) {
            float A = 0.f, L = 0.f;
#pragma unroll
            for (int cc2 = 0; cc2 < NSPL; ++cc2) {
                A += pacc[(((size_t)bh * NSPL + cc2) * Uu + s) * Dd + d];
                L += pl[((size_t)bh * NSPL + cc2) * Uu + s];
            }
            o = A / L;
        }
        ob[(size_t)l * (Hh * Dd)] = o;
    }
}

extern "C" void kernel_launch(void* const* d_in, const int* in_sizes, int n_in,
                              void* d_out, int out_size, void* d_ws, size_t ws_size,
                              hipStream_t stream) {
    const float* Qp   = (const float*)d_in[0];
    const float* Kp   = (const float*)d_in[1];
    const float* Vp   = (const float*)d_in[2];
    const int*   idxs = (const int*)d_in[3];
    float* out = (float*)d_out;

    char* w = (char*)d_ws;
    float* M    = (float*)(w);                 // 512K
    int*   sel  = (int*)  (w + 512 * 1024);    // 512K
    int*   Mtop = (int*)  (w + 1664 * 1024);   // 16K
    float* part = (float*)(w + 1680 * 1024);   // 512K
    float* pacc = (float*)(w + 2304 * 1024);   // 5120K (64*8*40*64 f)
    float* pl   = (float*)(w + 7424 * 1024);   // 80K

    k_sampleM<<<Bb * (LQ / 16), 256, 0, stream>>>(Qp, Kp, idxs, M);
    k_topk<<<Bb * Hh, 64, 0, stream>>>(M, Mtop, sel);
    k_attn_part<<<Bb * Hh * NSPL, 256, 0, stream>>>(Qp, Kp, Vp, Mtop, pacc, pl);
    k_part<<<Bb * Hh * NCH, 64, 0, stream>>>(Vp, part);
    k_scan<<<Bb * Hh * NCH, 64, 0, stream>>>(Vp, part, sel, pacc, pl, out);
}